// Round 8
// baseline (56.251 us; speedup 1.0000x reference)
//
#include <hip/hip_runtime.h>
#include <hip/hip_bf16.h>

// Problem constants: B=16, T=2048, D=512, HD=64, causal single-head attention.
#define NB   16
#define NT   2048
#define ND   512
#define NHD  64
// (1/sqrt(64)) * log2(e): folded into q so attention softmax uses exp2 directly.
#define QSCALE 0.1803368801111204f

typedef __attribute__((ext_vector_type(8))) short bf16x8;   // 8 bf16 in 4 VGPRs
typedef __attribute__((ext_vector_type(4))) short bf16x4;   // 8-byte pack
typedef __attribute__((ext_vector_type(4))) float f32x4;

static __device__ __forceinline__ short f2bf(float f) {
    union { __hip_bfloat16 h; short s; } u;
    u.h = __float2bfloat16(f);   // RNE; pairs into v_cvt_pk_bf16_f32
    return u.s;
}
static __device__ __forceinline__ float bf2f(short s) {
    union { unsigned u; float f; } x;
    x.u = ((unsigned)(unsigned short)s) << 16;
    return x.f;
}
// async global->LDS 16B: per-lane global src, wave-uniform-base+lane*16 LDS dst.
static __device__ __forceinline__ void gll16(const void* g, void* l) {
    __builtin_amdgcn_global_load_lds(
        (const __attribute__((address_space(1))) unsigned int*)g,
        (__attribute__((address_space(3))) unsigned int*)l, 16, 0, 0);
}

// ---------------------------------------------------------------------------
// Kernel 1: transpose W (f32 [512][64]) -> Wt (bf16 [3][64][512])
// ---------------------------------------------------------------------------
__global__ __launch_bounds__(256) void wtrans_kernel(
    const float* __restrict__ Wq, const float* __restrict__ Wk,
    const float* __restrict__ Wv, short* __restrict__ wt) {
    int tid = blockIdx.x * 256 + threadIdx.x;       // 0 .. 3*64*512-1
    int k = tid & (ND - 1);
    int c = (tid >> 9) & (NHD - 1);
    int m = tid >> 15;                              // 0..2
    const float* W = (m == 0) ? Wq : (m == 1) ? Wk : Wv;
    wt[tid] = f2bf(W[k * NHD + c]);                 // wt[(m*64+c)*512+k]
}

// ---------------------------------------------------------------------------
// Kernel 2: QKV projection as LDS-tiled GEMM (r6 version: BM=64, grid 512 --
// r7's BM=32 doubled redundant W traffic and was 1.4us slower).
// ---------------------------------------------------------------------------
__global__ __launch_bounds__(256, 4) void qkv_gemm_kernel(
    const float* __restrict__ x, const short* __restrict__ wt,
    short* __restrict__ qws, short* __restrict__ kws, short* __restrict__ vtws) {
    int t    = threadIdx.x;
    int lane = t & 63;
    int q16  = lane & 15;
    int g    = lane >> 4;
    int wv   = t >> 6;
    int wm   = wv >> 1, wn = wv & 1;
    long R0  = (long)blockIdx.x * 64;

    __shared__ __align__(16) short Xt[64 * 64];     // [token][k] 8KB swizzled
    __shared__ __align__(16) short Wl[192 * 64];    // [col][k]  24KB swizzled

    int xrow = t >> 4, xquad = t & 15;              // X: 4 rounds of 16 rows
    int wrow = t >> 3, wseg = t & 7;                // W: 6 rounds of 32 rows

    const float* xg = x + (R0 + xrow) * ND + xquad * 4;
    const short* wg = wt + wrow * ND + wseg * 8;

    f32x4 xr[4];
    bf16x8 wr[6];
    auto LOAD = [&](int ch) {
#pragma unroll
        for (int i = 0; i < 4; ++i)
            xr[i] = *(const f32x4*)(xg + (long)i * 16 * ND + ch * 64);
#pragma unroll
        for (int i = 0; i < 6; ++i)
            wr[i] = *(const bf16x8*)(wg + (long)i * 32 * ND + ch * 64);
    };
    auto STORE_LDS = [&]() {
#pragma unroll
        for (int i = 0; i < 4; ++i) {
            bf16x4 c;
#pragma unroll
            for (int j = 0; j < 4; ++j) c[j] = f2bf(xr[i][j]);
            int row = i * 16 + xrow;
            *(bf16x4*)((char*)Xt + row * 128 +
                       (((xquad >> 1) * 16) ^ ((row & 7) << 4)) + (xquad & 1) * 8) = c;
        }
#pragma unroll
        for (int i = 0; i < 6; ++i) {
            int row = i * 32 + wrow;
            *(bf16x8*)((char*)Wl + row * 128 + ((wseg * 16) ^ ((row & 7) << 4))) = wr[i];
        }
    };

    f32x4 acc[2][6];
#pragma unroll
    for (int mi = 0; mi < 2; ++mi)
#pragma unroll
        for (int ni = 0; ni < 6; ++ni) acc[mi][ni] = (f32x4){0.f, 0.f, 0.f, 0.f};

    LOAD(0);
    for (int ch = 0; ch < 8; ++ch) {
        STORE_LDS();
        if (ch + 1 < 8) LOAD(ch + 1);   // in flight during compute (T14)
        __syncthreads();
        __builtin_amdgcn_s_setprio(1);
#pragma unroll
        for (int kk = 0; kk < 2; ++kk) {
            bf16x8 a[2];
#pragma unroll
            for (int mi = 0; mi < 2; ++mi) {
                int row = wm * 32 + mi * 16 + q16;
                a[mi] = *(const bf16x8*)((char*)Xt + row * 128 +
                         ((kk * 64 + g * 16) ^ ((row & 7) << 4)));
            }
#pragma unroll
            for (int ni = 0; ni < 6; ++ni) {
                int row = wn * 96 + ni * 16 + q16;
                bf16x8 b = *(const bf16x8*)((char*)Wl + row * 128 +
                            ((kk * 64 + g * 16) ^ ((row & 7) << 4)));
                acc[0][ni] = __builtin_amdgcn_mfma_f32_16x16x32_bf16(a[0], b, acc[0][ni], 0, 0, 0);
                acc[1][ni] = __builtin_amdgcn_mfma_f32_16x16x32_bf16(a[1], b, acc[1][ni], 0, 0, 0);
            }
        }
        __builtin_amdgcn_s_setprio(0);
        __syncthreads();
    }

    int b = (int)(R0 >> 11);
#pragma unroll
    for (int mi = 0; mi < 2; ++mi) {
        long tok0 = R0 + wm * 32 + mi * 16 + g * 4;
#pragma unroll
        for (int ni = 0; ni < 6; ++ni) {
            int col = wn * 96 + ni * 16 + q16;
            int m = col >> 6, c64 = col & 63;       // uniform per (wn,ni)
            if (m == 0) {
#pragma unroll
                for (int r = 0; r < 4; ++r)
                    qws[(tok0 + r) * NHD + c64] = f2bf(acc[mi][ni][r] * QSCALE);
            } else if (m == 1) {
#pragma unroll
                for (int r = 0; r < 4; ++r)
                    kws[(tok0 + r) * NHD + c64] = f2bf(acc[mi][ni][r]);
            } else {
                bf16x4 vp;
#pragma unroll
                for (int r = 0; r < 4; ++r) vp[r] = f2bf(acc[mi][ni][r]);
                *(bf16x4*)(vtws + (long)(b * NHD + c64) * NT +
                           (int)(tok0 & 2047)) = vp;
            }
        }
    }
}

// ---------------------------------------------------------------------------
// Kernel 3: causal flash attention partial, QBLK=128 (32 q-rows/wave).
// r7 model: attn is LDS-BW + chain-latency bound; all 4 waves re-read the
// same K/V LDS tile. Serving 128 q-rows per tile halves K/V/staging traffic
// and barrier count per unit work. Per tile: read kf once -> MFMA both
// 16-row halves; softmax+P+PV sequential per half (same-wave LDS in-order
// makes the per-wave P buffer reuse safe). Fully-masked halves skip QK.
// KV-split x4 -> grid 1024 = 4 blocks/CU, 40KB LDS, VGPR<=128.
// ---------------------------------------------------------------------------
__global__ __launch_bounds__(256, 4) void attn_kernel(
    const short* __restrict__ qws, const short* __restrict__ kws,
    const short* __restrict__ vtws, short* __restrict__ Opart,
    float* __restrict__ lpart) {
    int bid  = blockIdx.x;
    int xcd  = bid & 7;
    int j    = bid >> 3;                // 0..127 within XCD
    int b    = xcd * 2 + (j >> 6);      // batch: 2 per XCD
    int r    = j & 63;
    int qt   = 15 - (r >> 2);           // heavy q-tiles first
    int s    = r & 3;                   // kv quarter
    int tid  = threadIdx.x;
    int lane = tid & 63;
    int wv   = tid >> 6;                // 0..3
    int qcol = lane & 15;
    int g    = lane >> 4;

    __shared__ __align__(16) short Kt[2][64 * 64];  // [key][hd]  2x8KB swizzled
    __shared__ __align__(16) short Vt[2][64 * 64];  // [hd][key]  2x8KB swizzled
    __shared__ __align__(16) short Pl[4][16 * 64];  // per-wave P [q][key] 8KB

    int qr0 = qt * 128 + wv * 32;       // wave's first q row

    // Q fragments for both 16-row halves (pre-scaled by QSCALE).
    const short* qb0 = qws + (long)(b * NT + qr0 + qcol) * NHD;
    const short* qb1 = qws + (long)(b * NT + qr0 + 16 + qcol) * NHD;
    bf16x8 qf00 = *(const bf16x8*)(qb0 + g * 8);
    bf16x8 qf01 = *(const bf16x8*)(qb0 + 32 + g * 8);
    bf16x8 qf10 = *(const bf16x8*)(qb1 + g * 8);
    bf16x8 qf11 = *(const bf16x8*)(qb1 + 32 + g * 8);

    // gll staging: linear LDS dest, XOR-permuted per-lane source (r6).
    int srow = tid >> 3, ssw = tid & 7;
    int seg  = ssw ^ (srow & 7);
    const char* kT = (const char*)(kws  + (long)b * NT * NHD);
    const char* vT = (const char*)(vtws + (long)b * NHD * NT);
    auto STAGE = [&](int kv0, int buf) {
        char* lk = (char*)Kt + buf * 8192 + tid * 16;
        char* lv = (char*)Vt + buf * 8192 + tid * 16;
        const char* gk = kT + (long)(kv0 + srow) * 128 + seg * 16;
        const char* gv = vT + (long)srow * 4096 + kv0 * 2 + seg * 16;
        gll16(gk, lk);
        gll16(gk + 32 * 128, lk + 4096);
        gll16(gv, lv);
        gll16(gv + 32 * 4096, lv + 4096);
    };

    int sw  = (qcol & 7) << 4;          // row&7 == qcol&7 for all rows we read
    char* pw = (char*)Pl[wv] + qcol * 128;

    int n   = 2 * qt + 2;               // kv tiles covering this q-tile
    int tlo = (s * n) >> 2;
    int thi = ((s + 1) * n) >> 2;

    f32x4 o0[4], o1[4];
#pragma unroll
    for (int h = 0; h < 4; ++h) {
        o0[h] = (f32x4){0.f, 0.f, 0.f, 0.f};
        o1[h] = (f32x4){0.f, 0.f, 0.f, 0.f};
    }
    float l0 = 0.f, l1 = 0.f;

    // softmax + P-write + PV for one 16-row half.
    auto HALF = [&](const f32x4* sreg, f32x4* o, float& l_run,
                    int qrow, bool msk, int k0, const char* vcur) {
        float pv[16];
        if (msk) {
#pragma unroll
            for (int ks = 0; ks < 4; ++ks)
#pragma unroll
                for (int rr = 0; rr < 4; ++rr) {
                    float tv = sreg[ks][rr];
                    if (k0 + ks * 16 + g * 4 + rr > qrow) tv = -1e30f;
                    pv[ks * 4 + rr] = exp2f(tv);
                }
        } else {
#pragma unroll
            for (int ks = 0; ks < 4; ++ks)
#pragma unroll
                for (int rr = 0; rr < 4; ++rr)
                    pv[ks * 4 + rr] = exp2f(sreg[ks][rr]);
        }
        short pb[16];
#pragma unroll
        for (int i = 0; i < 16; ++i) { l_run += pv[i]; pb[i] = f2bf(pv[i]); }
#pragma unroll
        for (int ks = 0; ks < 4; ++ks) {
            bf16x4 pk;
#pragma unroll
            for (int rr = 0; rr < 4; ++rr) pk[rr] = pb[ks * 4 + rr];
            *(bf16x4*)(pw + ((ks * 32 + g * 8) ^ sw)) = pk;
        }
        __builtin_amdgcn_s_setprio(1);
#pragma unroll
        for (int kc = 0; kc < 2; ++kc) {
            bf16x8 pf = *(const bf16x8*)(pw + ((kc * 64 + g * 16) ^ sw));
#pragma unroll
            for (int h = 0; h < 4; ++h) {
                bf16x8 vf = *(const bf16x8*)(vcur + (h * 16 + qcol) * 128 +
                             ((kc * 64 + g * 16) ^ sw));
                o[h] = __builtin_amdgcn_mfma_f32_16x16x32_bf16(vf, pf, o[h], 0, 0, 0);
            }
        }
        __builtin_amdgcn_s_setprio(0);
    };

    if (tlo < thi) {
        STAGE(tlo * 64, 0);
        __syncthreads();                // drains vmcnt(0): tile ready

        for (int kvi = tlo; kvi < thi; ++kvi) {
            int  cur = (kvi - tlo) & 1;
            bool pre = (kvi + 1 < thi);
            if (pre) STAGE((kvi + 1) * 64, cur ^ 1);    // fly under compute

            const char* kcur = (const char*)Kt + cur * 8192;
            const char* vcur = (const char*)Vt + cur * 8192;
            int k0 = kvi * 64;
            bool a0 = (k0 <= qr0 + 15);         // half 0 has unmasked keys
            bool a1 = (k0 <= qr0 + 31);         // half 1 has unmasked keys

            if (a1) {
                // ---- S^T = K · Q^T, kf shared by both halves ----
                f32x4 s0[4], s1[4];
                __builtin_amdgcn_s_setprio(1);
#pragma unroll
                for (int ks = 0; ks < 4; ++ks) {
                    const char* kb = kcur + (ks * 16 + qcol) * 128;
                    bf16x8 kf0 = *(const bf16x8*)(kb + ((g * 16) ^ sw));
                    bf16x8 kf1 = *(const bf16x8*)(kb + ((64 + g * 16) ^ sw));
                    f32x4 z;
                    if (a0) {
                        z = (f32x4){0.f, 0.f, 0.f, 0.f};
                        z = __builtin_amdgcn_mfma_f32_16x16x32_bf16(kf0, qf00, z, 0, 0, 0);
                        s0[ks] = __builtin_amdgcn_mfma_f32_16x16x32_bf16(kf1, qf01, z, 0, 0, 0);
                    }
                    z = (f32x4){0.f, 0.f, 0.f, 0.f};
                    z = __builtin_amdgcn_mfma_f32_16x16x32_bf16(kf0, qf10, z, 0, 0, 0);
                    s1[ks] = __builtin_amdgcn_mfma_f32_16x16x32_bf16(kf1, qf11, z, 0, 0, 0);
                }
                __builtin_amdgcn_s_setprio(0);

                if (a0) HALF(s0, o0, l0, qr0 + qcol,      k0 + 63 > qr0,      k0, vcur);
                        HALF(s1, o1, l1, qr0 + 16 + qcol, k0 + 63 > qr0 + 16, k0, vcur);
            }

            if (pre) __syncthreads();   // drains next tile's gll + protects bufs
        }
    }

    // ---- epilogue: reduce l once; UNNORMALIZED bf16 partial O^T ----
    l0 += __shfl_xor(l0, 16); l0 += __shfl_xor(l0, 32);
    l1 += __shfl_xor(l1, 16); l1 += __shfl_xor(l1, 32);
    long prow0 = (long)s * 32768 + (b << 11) + qt * 128 + wv * 32 + qcol;
    long prow1 = prow0 + 16;
#pragma unroll
    for (int h = 0; h < 4; ++h) {
        bf16x4 ob0, ob1;
#pragma unroll
        for (int rr = 0; rr < 4; ++rr) { ob0[rr] = f2bf(o0[h][rr]); ob1[rr] = f2bf(o1[h][rr]); }
        *(bf16x4*)(Opart + prow0 * 64 + h * 16 + g * 4) = ob0;
        *(bf16x4*)(Opart + prow1 * 64 + h * 16 + g * 4) = ob1;
    }
    if (g == 0) { lpart[prow0] = l0; lpart[prow1] = l1; }
}

// ---------------------------------------------------------------------------
// Kernel 4: merge the four KV-quarter partials: out = sum(Oi)/sum(li).
// ---------------------------------------------------------------------------
__global__ __launch_bounds__(256) void merge_kernel(
    const short* __restrict__ Opart, const float* __restrict__ lpart,
    float* __restrict__ out) {
    int idx  = blockIdx.x * 256 + threadIdx.x;      // 0 .. 262143
    int ridx = idx >> 3;                            // output row (== partial row)
    int h8   = idx & 7;                             // 8-hd chunk
    float lsum = lpart[ridx] + lpart[32768 + ridx] +
                 lpart[65536 + ridx] + lpart[98304 + ridx];
    float inv = 1.0f / lsum;
    f32x4 r0 = (f32x4){0.f, 0.f, 0.f, 0.f};
    f32x4 r1 = (f32x4){0.f, 0.f, 0.f, 0.f};
#pragma unroll
    for (int s = 0; s < 4; ++s) {
        bf16x8 a = *(const bf16x8*)(Opart + (long)s * 2097152 + (long)ridx * 64 + h8 * 8);
#pragma unroll
        for (int jj = 0; jj < 4; ++jj) {
            r0[jj] += bf2f(a[jj]);
            r1[jj] += bf2f(a[4 + jj]);
        }
    }
    r0 *= inv; r1 *= inv;
    float* dst = out + (long)ridx * 64 + h8 * 8;
    *(f32x4*)dst = r0;
    *(f32x4*)(dst + 4) = r1;
}

// ---------------------------------------------------------------------------
extern "C" void kernel_launch(void* const* d_in, const int* in_sizes, int n_in,
                              void* d_out, int out_size, void* d_ws, size_t ws_size,
                              hipStream_t stream) {
    const float* x  = (const float*)d_in[0];
    const float* Wq = (const float*)d_in[1];
    const float* Wk = (const float*)d_in[2];
    const float* Wv = (const float*)d_in[3];
    float* out = (float*)d_out;

    float* fb    = (float*)d_ws;
    float* lpart = fb;                              // 4*32768 f32 (512KB)
    short* Opart = (short*)(fb + 131072);           // 4*32768*64 bf16 (16MB)
    short* qws   = Opart + (long)4 * 2097152;       // [32768][64] bf16 (pre-scaled)
    short* kws   = qws + (long)2097152;             // [32768][64] bf16
    short* vtws  = kws + (long)2097152;             // [16][64][2048] bf16
    short* wt    = vtws + (long)2097152;            // [3][64][512] bf16

    wtrans_kernel<<<384, 256, 0, stream>>>(Wq, Wk, Wv, wt);
    qkv_gemm_kernel<<<512, 256, 0, stream>>>(x, wt, qws, kws, vtws);
    attn_kernel<<<1024, 256, 0, stream>>>(qws, kws, vtws, Opart, lpart);
    merge_kernel<<<1024, 256, 0, stream>>>(Opart, lpart, out);
}